// Round 10
// baseline (502.622 us; speedup 1.0000x reference)
//
#include <hip/hip_runtime.h>
#include <hip/hip_fp16.h>

typedef __attribute__((ext_vector_type(4))) float f32x4;

#define NROWS 8192
#define DCOLS 256
#define MARGIN 0.5f
#define NT 64          // 8192/128 tiles per dim
#define NBLOCKS 544    // sum over rows bi of ceil((64-bi)/4) runs of <=4 j-tiles

// --- Kernel 1: L2-normalize rows fp32 -> fp8 e5m2 (= truncated fp16), row-major.
__global__ __launch_bounds__(256) void norm_kernel(const float* __restrict__ x,
                                                   unsigned char* __restrict__ e) {
    const int t = threadIdx.x;
    const int l = t & 63;
    const int c = l & 31;
    const int row = blockIdx.x * 8 + (t >> 6) * 2 + (l >> 5);

    const float4 v0 = *reinterpret_cast<const float4*>(&x[row * DCOLS + c * 8]);
    const float4 v1 = *reinterpret_cast<const float4*>(&x[row * DCOLS + c * 8 + 4]);
    float ss = v0.x * v0.x + v0.y * v0.y + v0.z * v0.z + v0.w * v0.w
             + v1.x * v1.x + v1.y * v1.y + v1.z * v1.z + v1.w * v1.w;
#pragma unroll
    for (int off = 16; off >= 1; off >>= 1) ss += __shfl_xor(ss, off, 32);
    const float inv = 1.0f / fmaxf(sqrtf(ss), 1e-12f);

    const float f[8] = {v0.x, v0.y, v0.z, v0.w, v1.x, v1.y, v1.z, v1.w};
    unsigned int lo = 0, hi = 0;
#pragma unroll
    for (int i = 0; i < 4; ++i) {
        const unsigned short hb = __half_as_ushort(__float2half(f[i] * inv));
        lo |= (unsigned int)(hb >> 8) << (8 * i);           // e5m2 = fp16 top byte
    }
#pragma unroll
    for (int i = 0; i < 4; ++i) {
        const unsigned short hb = __half_as_ushort(__float2half(f[4 + i] * inv));
        hi |= (unsigned int)(hb >> 8) << (8 * i);
    }
    uint2 o; o.x = lo; o.y = hi;
    *reinterpret_cast<uint2*>(e + (size_t)row * DCOLS + c * 8) = o;
}

// Stage one 128x32 fp8 B panel (4 KB). Blob layout: blob[g] (16-row group) =
// 512 B; chunk cc = row (cc>>1), k-half (cc&1). Lane (lr,hk) reads b64 at
// blob + lr*32 + hk*8. Linear LDS dest = base + tid*16 (rule #21).
__device__ __forceinline__ void stage_B(const unsigned char* __restrict__ ebase,
                                        char* Bbuf, int kt, int tid) {
    const int g  = tid >> 5;
    const int cc = tid & 31;
    const int go = (g * 16 + (cc >> 1)) * DCOLS + kt * 32 + (cc & 1) * 16;
    __builtin_amdgcn_global_load_lds(
        (const __attribute__((address_space(1))) void*)(ebase + go),
        (__attribute__((address_space(3))) void*)(Bbuf + tid * 16), 16, 0, 0);
}

// --- Kernel 2: persistent run-blocks, ring-8 B panels (H1 fix: 7 outstanding
// loads/thread, waits reference loads issued 7 steps (~1500+ cyc) back).
// A (128 x K=256 fp8, 32 KB) staged once. 4 waves (2x2), wave tile 64x64,
// 16x16x32 bf8_bf8. 64 KB LDS -> 2 blocks/CU.
__global__ __launch_bounds__(256, 2) void tile_kernel(const unsigned char* __restrict__ e,
                                                      float* __restrict__ part) {
    const int orig = blockIdx.x;
    int bb = (orig & 7) * 68 + (orig >> 3);
    int bi = 0;
    while (bb >= ((NT - bi) + 3) >> 2) { bb -= ((NT - bi) + 3) >> 2; ++bi; }
    const int j0 = bi + bb * 4;
    const int nj = min(4, NT - j0);
    const int NS = nj * 8;                    // B K-step stream length (mult of 8)

    __shared__ char As[32768];                // A: [kt 0..7][g 0..7][512 B]
    __shared__ char Bring[8][4096];           // B ring-8
    __shared__ float red[4];

    const int t = threadIdx.x;
    const int l = t & 63;
    const int w = t >> 6;
    const int wr = w >> 1;
    const int wc = w & 1;
    const int lr = l & 15;
    const int hk = l >> 4;
    const int lane_off = lr * 32 + hk * 8;

    const unsigned char* eA = e + (size_t)bi * 128 * DCOLS;

    // prologue: full-K A (8 loads/thread), then B steps 0..6 -> slots 0..6
#pragma unroll
    for (int i = 0; i < 8; ++i) {
        const int u  = i * 256 + t;
        const int kt = u >> 8, g = (u >> 5) & 7, cc = u & 31;
        const int go = (g * 16 + (cc >> 1)) * DCOLS + kt * 32 + (cc & 1) * 16;
        __builtin_amdgcn_global_load_lds(
            (const __attribute__((address_space(1))) void*)(eA + go),
            (__attribute__((address_space(3))) void*)(As + u * 16), 16, 0, 0);
    }
#pragma unroll
    for (int p = 0; p < 7; ++p)   // p < 7 <= NS always
        stage_B(e + (size_t)(j0 + (p >> 3)) * 128 * DCOLS, Bring[p], p & 7, t);

    f32x4 acc[4][4];
#pragma unroll
    for (int m = 0; m < 4; ++m)
#pragma unroll
        for (int n = 0; n < 4; ++n)
            acc[m][n] = (f32x4){0.f, 0.f, 0.f, 0.f};

    float local = 0.0f;
    for (int s = 0; s < NS; ++s) {
        const int kt = s & 7;
        const int jt = j0 + (s >> 3);
        // 7 outstanding; wait oldest (this step's panel, issued 7 steps ago)
        asm volatile("s_waitcnt vmcnt(6)" ::: "memory");
        __builtin_amdgcn_s_barrier();
        // stage step s+7 (wrap: writes land in slot (s-1)&7, read-complete,
        // never read again -> safe; keeps outstanding count uniform)
        int s7 = s + 7; if (s7 >= NS) s7 -= NS;
        stage_B(e + (size_t)(j0 + (s7 >> 3)) * 128 * DCOLS, Bring[s7 & 7], s7 & 7, t);

        long af[4], bf[4];
#pragma unroll
        for (int m = 0; m < 4; ++m)
            af[m] = *reinterpret_cast<const long*>(
                As + kt * 4096 + (wr * 4 + m) * 512 + lane_off);
#pragma unroll
        for (int n = 0; n < 4; ++n)
            bf[n] = *reinterpret_cast<const long*>(
                Bring[s & 7] + (wc * 4 + n) * 512 + lane_off);
        __builtin_amdgcn_s_setprio(1);
#pragma unroll
        for (int m = 0; m < 4; ++m)
#pragma unroll
            for (int n = 0; n < 4; ++n)
                acc[m][n] = __builtin_amdgcn_mfma_f32_16x16x32_bf8_bf8(
                    af[m], bf[n], acc[m][n], 0, 0, 0);
        __builtin_amdgcn_s_setprio(0);

        if (kt == 7) {   // tile done: fused masked-relu reduce, reset acc
            const int gi0 = bi * 128 + wr * 64;
            const int gj0 = jt * 128 + wc * 64;
            if (jt == bi) {
#pragma unroll
                for (int m = 0; m < 4; ++m)
#pragma unroll
                    for (int n = 0; n < 4; ++n) {
#pragma unroll
                        for (int r = 0; r < 4; ++r) {
                            const int gi = gi0 + m * 16 + hk * 4 + r;
                            const int gj = gj0 + n * 16 + lr;
                            local += (gi < gj) ? fmaxf(acc[m][n][r] - MARGIN, 0.0f) : 0.0f;
                        }
                        acc[m][n] = (f32x4){0.f, 0.f, 0.f, 0.f};
                    }
            } else {
#pragma unroll
                for (int m = 0; m < 4; ++m)
#pragma unroll
                    for (int n = 0; n < 4; ++n) {
#pragma unroll
                        for (int r = 0; r < 4; ++r)
                            local += fmaxf(acc[m][n][r] - MARGIN, 0.0f);
                        acc[m][n] = (f32x4){0.f, 0.f, 0.f, 0.f};
                    }
            }
        }
    }

#pragma unroll
    for (int off = 32; off >= 1; off >>= 1) local += __shfl_down(local, off);
    if (l == 0) red[w] = local;
    __syncthreads();
    if (t == 0) part[orig] = red[0] + red[1] + red[2] + red[3];
}

// --- Kernel 3: reduce NBLOCKS partials, finalize ---
__global__ __launch_bounds__(256) void fin_kernel(const float* __restrict__ part,
                                                  float* __restrict__ out) {
    __shared__ float red[4];
    const int t = threadIdx.x;
    float v = part[t] + part[t + 256] + (t < NBLOCKS - 512 ? part[t + 512] : 0.0f);
#pragma unroll
    for (int off = 32; off >= 1; off >>= 1) v += __shfl_down(v, off);
    if ((t & 63) == 0) red[t >> 6] = v;
    __syncthreads();
    if (t == 0) out[0] = (red[0] + red[1] + red[2] + red[3]) / 33550336.0f;
}

// ===================== DIAGNOSTIC PROBES (dead scratch output) ==============

// P1: barrier'd MFMA pipeline at real sync density, no global traffic in loop.
// 768 steps x 16 MFMA. Expect ~50-60 us if MFMA+barrier healthy.
__global__ __launch_bounds__(256) void probe_mfma(const unsigned char* __restrict__ e,
                                                  float* __restrict__ scr) {
    __shared__ char As[4096];
    const int t = threadIdx.x;
    __builtin_amdgcn_global_load_lds(
        (const __attribute__((address_space(1))) void*)(e + t * 16),
        (__attribute__((address_space(3))) void*)(As + t * 16), 16, 0, 0);
    asm volatile("s_waitcnt vmcnt(0)" ::: "memory");
    __builtin_amdgcn_s_barrier();

    const int l = t & 63;
    const int lane_off = (l & 15) * 32 + (l >> 4) * 8;
    long af[4], bf[4];
#pragma unroll
    for (int m = 0; m < 4; ++m) af[m] = *reinterpret_cast<const long*>(As + m * 512 + lane_off);
#pragma unroll
    for (int n = 0; n < 4; ++n) bf[n] = *reinterpret_cast<const long*>(As + (4 + n) * 512 + lane_off);

    f32x4 acc[4][4];
#pragma unroll
    for (int m = 0; m < 4; ++m)
#pragma unroll
        for (int n = 0; n < 4; ++n) acc[m][n] = (f32x4){0.f, 0.f, 0.f, 0.f};

    for (int s = 0; s < 768; ++s) {
        __builtin_amdgcn_s_barrier();
        __builtin_amdgcn_s_setprio(1);
#pragma unroll
        for (int m = 0; m < 4; ++m)
#pragma unroll
            for (int n = 0; n < 4; ++n)
                acc[m][n] = __builtin_amdgcn_mfma_f32_16x16x32_bf8_bf8(
                    af[m], bf[n], acc[m][n], 0, 0, 0);
        __builtin_amdgcn_s_setprio(0);
    }
    float x = 0.f;
#pragma unroll
    for (int m = 0; m < 4; ++m)
#pragma unroll
        for (int n = 0; n < 4; ++n)
            x += acc[m][n][0] + acc[m][n][1] + acc[m][n][2] + acc[m][n][3];
    scr[blockIdx.x * 256 + t] = x;
}

// P2/P3: stage-only counted-vmcnt ring (RING=8 vs RING=4 = R9's exact depth).
// 512 steps, 1 global_load_lds per thread per step. Within-probe depth A/B.
template <int RING>
__global__ __launch_bounds__(256) void probe_stage(const unsigned char* __restrict__ e,
                                                   float* __restrict__ tok) {
    __shared__ char Bring[RING][4096];
    const int t = threadIdx.x;
    const int bi = blockIdx.x & 63;
#pragma unroll
    for (int p = 0; p < RING - 1; ++p)
        stage_B(e + (size_t)((bi + (p >> 3)) & 63) * 128 * DCOLS, Bring[p], p & 7, t);
    for (int s = 0; s < 512; ++s) {
        if constexpr (RING == 8) asm volatile("s_waitcnt vmcnt(6)" ::: "memory");
        else                     asm volatile("s_waitcnt vmcnt(2)" ::: "memory");
        __builtin_amdgcn_s_barrier();
        const int s2 = s + RING - 1;
        stage_B(e + (size_t)((bi + ((s2 >> 3) & 63)) & 63) * 128 * DCOLS,
                Bring[s2 & (RING - 1)], s2 & 7, t);
    }
    if (t == 0) tok[blockIdx.x] = 1.0f;
}

extern "C" void kernel_launch(void* const* d_in, const int* in_sizes, int n_in,
                              void* d_out, int out_size, void* d_ws, size_t ws_size,
                              hipStream_t stream) {
    const float* x = (const float*)d_in[0];
    float* out = (float*)d_out;
    unsigned char* e = (unsigned char*)d_ws;                        // 2 MB fp8
    float* part = (float*)((char*)d_ws + (size_t)NROWS * DCOLS);    // 544 floats
    float* scr  = (float*)((char*)d_ws + (16u << 20));              // probe scratch
    float* tok8 = (float*)((char*)d_ws + (24u << 20));
    float* tok4 = (float*)((char*)d_ws + (25u << 20));

    norm_kernel<<<NROWS / 8, 256, 0, stream>>>(x, e);
    tile_kernel<<<NBLOCKS, 256, 0, stream>>>(e, part);
    fin_kernel<<<1, 256, 0, stream>>>(part, out);
    // diagnostics (dead outputs; after fin so the result path is undisturbed)
    probe_mfma<<<NBLOCKS, 256, 0, stream>>>(e, scr);
    probe_stage<8><<<NBLOCKS, 256, 0, stream>>>(e, tok8);
    probe_stage<4><<<NBLOCKS, 256, 0, stream>>>(e, tok4);
}

// Round 11
// 44.489 us; speedup vs baseline: 11.2976x; 11.2976x over previous
//
#include <hip/hip_runtime.h>
#include <hip/hip_fp16.h>

typedef __attribute__((ext_vector_type(4))) float f32x4;

#define NROWS 8192
#define DCOLS 256
#define MARGIN 0.5f
#define NT 64          // 8192/128 tiles per dim
#define NBLOCKS 544    // sum over rows bi of ceil((64-bi)/4) runs of <=4 j-tiles

// --- Kernel 1: L2-normalize rows fp32 -> fp8 e5m2 (= truncated fp16), row-major.
__global__ __launch_bounds__(256) void norm_kernel(const float* __restrict__ x,
                                                   unsigned char* __restrict__ e) {
    const int t = threadIdx.x;
    const int l = t & 63;
    const int c = l & 31;
    const int row = blockIdx.x * 8 + (t >> 6) * 2 + (l >> 5);

    const float4 v0 = *reinterpret_cast<const float4*>(&x[row * DCOLS + c * 8]);
    const float4 v1 = *reinterpret_cast<const float4*>(&x[row * DCOLS + c * 8 + 4]);
    float ss = v0.x * v0.x + v0.y * v0.y + v0.z * v0.z + v0.w * v0.w
             + v1.x * v1.x + v1.y * v1.y + v1.z * v1.z + v1.w * v1.w;
#pragma unroll
    for (int off = 16; off >= 1; off >>= 1) ss += __shfl_xor(ss, off, 32);
    const float inv = 1.0f / fmaxf(sqrtf(ss), 1e-12f);

    const float f[8] = {v0.x, v0.y, v0.z, v0.w, v1.x, v1.y, v1.z, v1.w};
    unsigned int lo = 0, hi = 0;
#pragma unroll
    for (int i = 0; i < 4; ++i) {
        const unsigned short hb = __half_as_ushort(__float2half(f[i] * inv));
        lo |= (unsigned int)(hb >> 8) << (8 * i);           // e5m2 = fp16 top byte
    }
#pragma unroll
    for (int i = 0; i < 4; ++i) {
        const unsigned short hb = __half_as_ushort(__float2half(f[4 + i] * inv));
        hi |= (unsigned int)(hb >> 8) << (8 * i);
    }
    uint2 o; o.x = lo; o.y = hi;
    *reinterpret_cast<uint2*>(e + (size_t)row * DCOLS + c * 8) = o;
}

// Stage one 128x32 fp8 B panel (4 KB) with 256 threads (waves 0..3 only).
// Blob layout: blob[g] (16-row group, 0..7) = 512 B; chunk cc = (row cc>>1,
// k-half cc&1). Lane (lr,hk) reads b64 at blob + lr*32 + hk*8.
// Linear LDS dest = base + tid*16 (rule #21).
__device__ __forceinline__ void stage_B(const unsigned char* __restrict__ ebase,
                                        char* Bbuf, int kt, int tid) {
    const int g  = tid >> 5;
    const int cc = tid & 31;
    const int go = (g * 16 + (cc >> 1)) * DCOLS + kt * 32 + (cc & 1) * 16;
    __builtin_amdgcn_global_load_lds(
        (const __attribute__((address_space(1))) void*)(ebase + go),
        (__attribute__((address_space(3))) void*)(Bbuf + tid * 16), 16, 0, 0);
}

// --- Kernel 2: persistent run-blocks, A-in-registers, 4 waves/SIMD.
// Block = (bi, run of <=4 j-tiles). 8 waves (4M x 2N), wave tile 32x64,
// acc[2][4] of 16x16x32 bf8_bf8. A panel (128 x K=256 fp8) staged to LDS once,
// hoisted to af[8][2] registers (32 VGPR), LDS A then dead. B panels (4 KB per
// BK=32 step) stream through a ring-8 with counted vmcnt(6) (T4): producers
// (waves 0..3) wait only the oldest load (issued 7 steps back), never drain.
// Per step per wave: 4 b64 LDS reads + 8 MFMA (A from regs).
__global__ __launch_bounds__(512, 4) void tile_kernel(const unsigned char* __restrict__ e,
                                                      float* __restrict__ part) {
    // XCD-chunked bijective remap (544 = 8*68)
    const int orig = blockIdx.x;
    int bb = (orig & 7) * 68 + (orig >> 3);
    int bi = 0;
    while (bb >= ((NT - bi) + 3) >> 2) { bb -= ((NT - bi) + 3) >> 2; ++bi; }
    const int j0 = bi + bb * 4;
    const int nj = min(4, NT - j0);
    const int NS = nj * 8;

    __shared__ char As[32768];                // A: [kt 0..7][g 0..7][512 B]
    __shared__ char Bring[8][4096];           // B ring-8
    __shared__ float red[8];

    const int t = threadIdx.x;
    const int l = t & 63;
    const int w = t >> 6;       // 0..7
    const int wm = w >> 1;      // 0..3: rows wm*32
    const int wn = w & 1;       // 0..1: cols wn*64
    const int lr = l & 15;
    const int hk = l >> 4;
    const int lane_off = lr * 32 + hk * 8;
    const bool producer = (w < 4);

    const unsigned char* eA = e + (size_t)bi * 128 * DCOLS;

    // --- prologue: stage full-K A (4 loads/thread, 512 threads) ---
#pragma unroll
    for (int i = 0; i < 4; ++i) {
        const int u  = i * 512 + t;           // 0..2047
        const int kt = u >> 8, g = (u >> 5) & 7, cc = u & 31;
        const int go = (g * 16 + (cc >> 1)) * DCOLS + kt * 32 + (cc & 1) * 16;
        __builtin_amdgcn_global_load_lds(
            (const __attribute__((address_space(1))) void*)(eA + go),
            (__attribute__((address_space(3))) void*)(As + u * 16), 16, 0, 0);
    }
    // B panels 0..6 staged by waves 0..3
    if (producer) {
#pragma unroll
        for (int p = 0; p < 7; ++p)   // p < 7 <= NS always
            stage_B(e + (size_t)(j0 + (p >> 3)) * 128 * DCOLS, Bring[p], p & 7, t);
    }
    // A visibility: producers wait their 4 A loads (7 B still in flight),
    // non-producers wait all their (A-only) loads; barrier publishes A.
    if (producer) asm volatile("s_waitcnt vmcnt(7)" ::: "memory");
    else          asm volatile("s_waitcnt vmcnt(0)" ::: "memory");
    __builtin_amdgcn_s_barrier();
    __builtin_amdgcn_sched_barrier(0);

    // --- hoist A fragments to registers (one-time; B loads still in flight) ---
    long af[8][2];
#pragma unroll
    for (int kt = 0; kt < 8; ++kt)
#pragma unroll
        for (int m = 0; m < 2; ++m)
            af[kt][m] = *reinterpret_cast<const long*>(
                As + kt * 4096 + (wm * 2 + m) * 512 + lane_off);

    f32x4 acc[2][4];
#pragma unroll
    for (int m = 0; m < 2; ++m)
#pragma unroll
        for (int n = 0; n < 4; ++n)
            acc[m][n] = (f32x4){0.f, 0.f, 0.f, 0.f};

    float local = 0.0f;
    for (int jx = 0; jx < nj; ++jx) {
        const int jt = j0 + jx;
#pragma unroll
        for (int kt = 0; kt < 8; ++kt) {
            // gate slot kt: producer's oldest outstanding load IS slot kt
            // (staged 7 steps back); consumers rely on producer wait + barrier.
            if (producer) asm volatile("s_waitcnt vmcnt(6)" ::: "memory");
            __builtin_amdgcn_s_barrier();
            __builtin_amdgcn_sched_barrier(0);
            // stage step s+7 into slot (kt+7)&7 = the slot read at step s-1
            // (read-complete before this barrier). Wrap-stages keep the
            // outstanding count uniform; wrapped writes are never read again.
            if (producer) {
                int s7 = jx * 8 + kt + 7;
                if (s7 >= NS) s7 -= NS;
                stage_B(e + (size_t)(j0 + (s7 >> 3)) * 128 * DCOLS,
                        Bring[(kt + 7) & 7], s7 & 7, t);
            }
            long bf[4];
#pragma unroll
            for (int n = 0; n < 4; ++n)
                bf[n] = *reinterpret_cast<const long*>(
                    Bring[kt] + (wn * 4 + n) * 512 + lane_off);
            __builtin_amdgcn_s_setprio(1);
#pragma unroll
            for (int m = 0; m < 2; ++m)
#pragma unroll
                for (int n = 0; n < 4; ++n)
                    acc[m][n] = __builtin_amdgcn_mfma_f32_16x16x32_bf8_bf8(
                        af[kt][m], bf[n], acc[m][n], 0, 0, 0);
            __builtin_amdgcn_s_setprio(0);
        }
        // --- tile jt complete: fused masked-relu reduce, reset acc ---
        // C/D layout (m89-verified, dtype-independent): col=lane&15,
        // row=(lane>>4)*4+reg.
        {
            const int gi0 = bi * 128 + wm * 32;
            const int gj0 = jt * 128 + wn * 64;
            if (jt == bi) {
#pragma unroll
                for (int m = 0; m < 2; ++m)
#pragma unroll
                    for (int n = 0; n < 4; ++n) {
#pragma unroll
                        for (int r = 0; r < 4; ++r) {
                            const int gi = gi0 + m * 16 + hk * 4 + r;
                            const int gj = gj0 + n * 16 + lr;
                            local += (gi < gj) ? fmaxf(acc[m][n][r] - MARGIN, 0.0f) : 0.0f;
                        }
                        acc[m][n] = (f32x4){0.f, 0.f, 0.f, 0.f};
                    }
            } else {   // jt > bi: all pairs strictly upper-triangular
#pragma unroll
                for (int m = 0; m < 2; ++m)
#pragma unroll
                    for (int n = 0; n < 4; ++n) {
#pragma unroll
                        for (int r = 0; r < 4; ++r)
                            local += fmaxf(acc[m][n][r] - MARGIN, 0.0f);
                        acc[m][n] = (f32x4){0.f, 0.f, 0.f, 0.f};
                    }
            }
        }
    }

    // --- block reduction -> one partial per block, no atomics ---
#pragma unroll
    for (int off = 32; off >= 1; off >>= 1) local += __shfl_down(local, off);
    if (l == 0) red[w] = local;
    __syncthreads();
    if (t == 0) {
        float s = 0.0f;
#pragma unroll
        for (int i = 0; i < 8; ++i) s += red[i];
        part[orig] = s;
    }
}

// --- Kernel 3: reduce NBLOCKS partials, finalize ---
__global__ __launch_bounds__(256) void fin_kernel(const float* __restrict__ part,
                                                  float* __restrict__ out) {
    __shared__ float red[4];
    const int t = threadIdx.x;
    float v = part[t] + part[t + 256] + (t < NBLOCKS - 512 ? part[t + 512] : 0.0f);
#pragma unroll
    for (int off = 32; off >= 1; off >>= 1) v += __shfl_down(v, off);
    if ((t & 63) == 0) red[t >> 6] = v;
    __syncthreads();
    if (t == 0) out[0] = (red[0] + red[1] + red[2] + red[3]) / 33550336.0f;
}

extern "C" void kernel_launch(void* const* d_in, const int* in_sizes, int n_in,
                              void* d_out, int out_size, void* d_ws, size_t ws_size,
                              hipStream_t stream) {
    const float* x = (const float*)d_in[0];
    float* out = (float*)d_out;
    unsigned char* e = (unsigned char*)d_ws;                        // 2 MB fp8
    float* part = (float*)((char*)d_ws + (size_t)NROWS * DCOLS);    // 544 floats

    norm_kernel<<<NROWS / 8, 256, 0, stream>>>(x, e);
    tile_kernel<<<NBLOCKS, 512, 0, stream>>>(e, part);
    fin_kernel<<<1, 256, 0, stream>>>(part, out);
}